// Round 7
// baseline (1377.691 us; speedup 1.0000x reference)
//
#include <hip/hip_runtime.h>
#include <hip/hip_bf16.h>
#include <math.h>

#define S_ 2048
#define DM_ 2048
#define CK 16          // chunk length
#define NCH (S_ / CK)  // 128 chunks

// Full-wave (64-lane) sum via DPP row_shr/row_bcast, broadcast via readlane.
__device__ __forceinline__ float wave_reduce_add_f32(float x) {
  float t;
  t = __int_as_float(__builtin_amdgcn_update_dpp(0, __float_as_int(x), 0x111, 0xf, 0xf, true)); x += t;
  t = __int_as_float(__builtin_amdgcn_update_dpp(0, __float_as_int(x), 0x112, 0xf, 0xf, true)); x += t;
  t = __int_as_float(__builtin_amdgcn_update_dpp(0, __float_as_int(x), 0x114, 0xf, 0xf, true)); x += t;
  t = __int_as_float(__builtin_amdgcn_update_dpp(0, __float_as_int(x), 0x118, 0xf, 0xf, true)); x += t;
  t = __int_as_float(__builtin_amdgcn_update_dpp(0, __float_as_int(x), 0x142, 0xa, 0xf, true)); x += t;
  t = __int_as_float(__builtin_amdgcn_update_dpp(0, __float_as_int(x), 0x143, 0xc, 0xf, true)); x += t;
  return __int_as_float(__builtin_amdgcn_readlane(__float_as_int(x), 63));
}

// ---------------------------------------------------------------------------
// K1: fused projections. proj row (stride 256): k(l2)@0 | v@64 | q(l2)@128 | a@192
// ---------------------------------------------------------------------------
__global__ __launch_bounds__(256) void k_proj(
    const float* __restrict__ x, const float* __restrict__ Wk,
    const float* __restrict__ Wv, const float* __restrict__ Wq,
    const float* __restrict__ Wa, const float* __restrict__ Wab,
    const float* __restrict__ lam, float* __restrict__ proj)
{
  __shared__ __align__(16) float xs[16 * 40];
  __shared__ __align__(16) float ws[32 * 260];
  const int tid = threadIdx.x;
  const int r0  = blockIdx.x * 16;
  const int ct  = tid & 63;
  const int rt  = tid >> 6;
  float acc[4][4];
  #pragma unroll
  for (int r = 0; r < 4; r++) { acc[r][0] = 0.f; acc[r][1] = 0.f; acc[r][2] = 0.f; acc[r][3] = 0.f; }

  const int sg = tid >> 3;
  const int sm = tid & 7;
  const float* wbase[4] = {Wk, Wv, Wq, Wa};

  for (int k0 = 0; k0 < DM_; k0 += 32) {
    if (tid < 128) {
      const int rr = tid >> 3;
      const int ko = (tid & 7) << 2;
      float4 xv = *(const float4*)(x + (size_t)(r0 + rr) * DM_ + k0 + ko);
      *(float4*)(xs + rr * 40 + ko) = xv;
    }
    #pragma unroll
    for (int p = 0; p < 8; p++) {
      const int c = sg + p * 32;
      const float* wb = wbase[p >> 1];
      const int cc = c - (p >> 1) * 64;
      float4 wv = *(const float4*)(wb + (size_t)cc * DM_ + k0 + sm * 4);
      ws[(sm * 4 + 0) * 260 + c] = wv.x;
      ws[(sm * 4 + 1) * 260 + c] = wv.y;
      ws[(sm * 4 + 2) * 260 + c] = wv.z;
      ws[(sm * 4 + 3) * 260 + c] = wv.w;
    }
    __syncthreads();
    #pragma unroll
    for (int kq = 0; kq < 8; kq++) {
      float4 xv[4];
      #pragma unroll
      for (int r = 0; r < 4; r++) xv[r] = *(const float4*)(xs + (rt * 4 + r) * 40 + kq * 4);
      #pragma unroll
      for (int i = 0; i < 4; i++) {
        const int kk = kq * 4 + i;
        float wv0 = ws[kk * 260 + ct];
        float wv1 = ws[kk * 260 + ct + 64];
        float wv2 = ws[kk * 260 + ct + 128];
        float wv3 = ws[kk * 260 + ct + 192];
        #pragma unroll
        for (int r = 0; r < 4; r++) {
          float xr = (i == 0) ? xv[r].x : (i == 1) ? xv[r].y : (i == 2) ? xv[r].z : xv[r].w;
          acc[r][0] = fmaf(xr, wv0, acc[r][0]);
          acc[r][1] = fmaf(xr, wv1, acc[r][1]);
          acc[r][2] = fmaf(xr, wv2, acc[r][2]);
          acc[r][3] = fmaf(xr, wv3, acc[r][3]);
        }
      }
    }
    __syncthreads();
  }
  float lamv = lam[ct];
  float la = logf(1.f / (1.f + expf(-lamv)) + 1e-8f);
  float bv = Wab[ct];
  #pragma unroll
  for (int r = 0; r < 4; r++) {
    float nk = wave_reduce_add_f32(acc[r][0] * acc[r][0]);
    float nq = wave_reduce_add_f32(acc[r][2] * acc[r][2]);
    nk = fmaxf(sqrtf(nk), 1e-12f);
    nq = fmaxf(sqrtf(nq), 1e-12f);
    float pre = acc[r][3] + bv;
    float rr_ = 1.f / (1.f + expf(-pre));
    float al  = expf(8.f * rr_ * la);
    float* pr = proj + (size_t)(r0 + rt * 4 + r) * 256;
    pr[ct]        = acc[r][0] / nk;
    pr[64 + ct]   = acc[r][1];
    pr[128 + ct]  = acc[r][2] / nq;
    pr[192 + ct]  = al;
  }
}

// ---------------------------------------------------------------------------
// K2: chunked scan (C=16). 1 block/batch, 4 waves; wave w owns H rows
// [16w,16w+16), lane = v. Per chunk: prefix products + tables (parallel),
// base dots vs fixed H0 + CxC coeff GEMM-lets (parallel), then a 16-step
// serial recurrence that is ENTIRELY intra-wave (redundant across waves,
// zero barriers), then rank-16 H update + y assembly (parallel).
// 4 barriers per chunk instead of 2048 step barriers.
// ---------------------------------------------------------------------------
__global__ __launch_bounds__(256, 1) void k_scan(const float* __restrict__ proj,
                                                 float* __restrict__ ypart)
{
  __shared__ __align__(16) float slab[CK * 256];   // chunk inputs  16 KB
  __shared__ __align__(16) float qt [CK * 68];     // q~ = q*P_s    (pad 68)
  __shared__ __align__(16) float kt2[CK * 68];     // k~ = k*P_s
  __shared__ __align__(16) float wt [CK * 68];     // w~ = (1-a)k / P_{s+1}
  __shared__ __align__(16) float Pt [CK * 64];     // Pt[s][k] = P_{s+1}[k]
  __shared__ __align__(16) float H0t[64 * 64];     // H0 table      16 KB
  __shared__ __align__(16) float QKb[CK * 64 * 2]; // base dots interleaved {q,k}
  __shared__ __align__(16) float Yb [CK * 64];     // y base dots
  __shared__ __align__(16) float QCm[256], KCm[256], YCm[256];

  const int b = blockIdx.x, tid = threadIdx.x;
  const int w = tid >> 6, lane = tid & 63;
  const float* pb = proj + (size_t)b * S_ * 256;
  float* yb = ypart + (size_t)b * S_ * 64;

  float H[16];
  #pragma unroll
  for (int j = 0; j < 16; j++) H[j] = 0.f;
  #pragma unroll
  for (int i = 0; i < 16; i++) H0t[i * 256 + tid] = 0.f;
  float pf[16];                                    // next-chunk column (reg)
  #pragma unroll
  for (int i = 0; i < 16; i++) pf[i] = pb[i * 256 + tid];

  for (int n = 0; n < NCH; n++) {
    const int t0 = n << 4;
    // ---- ph1a: registers -> slab; wave 3 (holds the a-columns) does the
    //      prefix products from registers; then issue next-chunk loads.
    #pragma unroll
    for (int i = 0; i < 16; i++) slab[i * 256 + tid] = pf[i];
    if (tid >= 192) {
      const int k = tid - 192;
      float p = 1.f;
      #pragma unroll
      for (int s = 0; s < 16; s++) { p *= pf[s]; Pt[s * 64 + k] = p; }
    }
    #pragma unroll
    for (int i = 0; i < 16; i++) {
      int tt = t0 + 16 + i; tt = tt < S_ ? tt : S_ - 1;
      pf[i] = pb[(size_t)tt * 256 + tid];
    }
    __syncthreads();   // slab + Pt ready
    // ---- ph1c: tables. thread = (s = tid>>4, kq = (tid&15)*4)
    {
      const int s  = tid >> 4;
      const int kq = (tid & 15) << 2;
      float4 qv = *(const float4*)&slab[s * 256 + 128 + kq];
      float4 av = *(const float4*)&slab[s * 256 + 192 + kq];
      float4 kv = *(const float4*)&slab[s * 256 + 0   + kq];
      float4 P1 = *(const float4*)&Pt[s * 64 + kq];
      float4 P0;
      if (s == 0) { P0.x = P0.y = P0.z = P0.w = 1.f; }
      else        { P0 = *(const float4*)&Pt[(s - 1) * 64 + kq]; }
      float4 qtv, ktv, wtv;
      qtv.x = qv.x * P0.x; qtv.y = qv.y * P0.y; qtv.z = qv.z * P0.z; qtv.w = qv.w * P0.w;
      ktv.x = kv.x * P0.x; ktv.y = kv.y * P0.y; ktv.z = kv.z * P0.z; ktv.w = kv.w * P0.w;
      wtv.x = (1.f - av.x) * kv.x / P1.x;
      wtv.y = (1.f - av.y) * kv.y / P1.y;
      wtv.z = (1.f - av.z) * kv.z / P1.z;
      wtv.w = (1.f - av.w) * kv.w / P1.w;
      *(float4*)&qt [s * 68 + kq] = qtv;
      *(float4*)&kt2[s * 68 + kq] = ktv;
      *(float4*)&wt [s * 68 + kq] = wtv;
    }
    __syncthreads();   // tables ready
    // ---- ph2a: base dots vs H0. wave w owns t in {w, w+4, w+8, w+12}.
    {
      float aq[4] = {0.f, 0.f, 0.f, 0.f};
      float ak[4] = {0.f, 0.f, 0.f, 0.f};
      float ay[4] = {0.f, 0.f, 0.f, 0.f};
      #pragma unroll
      for (int kb = 0; kb < 16; kb++) {
        float h0 = H0t[(kb * 4 + 0) * 64 + lane];
        float h1 = H0t[(kb * 4 + 1) * 64 + lane];
        float h2 = H0t[(kb * 4 + 2) * 64 + lane];
        float h3 = H0t[(kb * 4 + 3) * 64 + lane];
        #pragma unroll
        for (int i = 0; i < 4; i++) {
          const int t = w + (i << 2);
          float4 qv = *(const float4*)&qt [t * 68 + kb * 4];
          float4 kv = *(const float4*)&kt2[t * 68 + kb * 4];
          float4 av = *(const float4*)&slab[t * 256 + 192 + kb * 4];
          aq[i] = fmaf(qv.x, h0, fmaf(qv.y, h1, fmaf(qv.z, h2, fmaf(qv.w, h3, aq[i]))));
          ak[i] = fmaf(kv.x, h0, fmaf(kv.y, h1, fmaf(kv.z, h2, fmaf(kv.w, h3, ak[i]))));
          ay[i] = fmaf(qv.x * av.x, h0, fmaf(qv.y * av.y, h1,
                  fmaf(qv.z * av.z, h2, fmaf(qv.w * av.w, h3, ay[i]))));
        }
      }
      #pragma unroll
      for (int i = 0; i < 4; i++) {
        const int t = w + (i << 2);
        *(float2*)&QKb[(t * 64 + lane) * 2] = make_float2(aq[i], ak[i]);
        Yb[t * 64 + lane] = ay[i];
      }
    }
    // ---- ph2b: coefficient matrices. thread = (t = tid>>4, s = tid&15).
    {
      const int t = tid >> 4, s = tid & 15;
      float accq = 0.f, acck = 0.f, accy = 0.f;
      #pragma unroll
      for (int kb = 0; kb < 16; kb++) {
        float4 wv = *(const float4*)&wt [s * 68 + kb * 4];
        float4 qv = *(const float4*)&qt [t * 68 + kb * 4];
        float4 kv = *(const float4*)&kt2[t * 68 + kb * 4];
        float4 av = *(const float4*)&slab[t * 256 + 192 + kb * 4];
        accq = fmaf(qv.x, wv.x, fmaf(qv.y, wv.y, fmaf(qv.z, wv.z, fmaf(qv.w, wv.w, accq))));
        acck = fmaf(kv.x, wv.x, fmaf(kv.y, wv.y, fmaf(kv.z, wv.z, fmaf(kv.w, wv.w, acck))));
        accy = fmaf(qv.x * av.x, wv.x, fmaf(qv.y * av.y, wv.y,
               fmaf(qv.z * av.z, wv.z, fmaf(qv.w * av.w, wv.w, accy))));
      }
      QCm[tid] = accq; KCm[tid] = acck; YCm[tid] = accy;
    }
    __syncthreads();   // bases + coeffs ready
    // ---- ph3: serial recurrence — intra-wave only, redundant across waves.
    float g[16];
    #pragma unroll
    for (int t = 0; t < 16; t++) {
      float qrow[16], krow[16];
      *(float4*)&qrow[0]  = *(const float4*)&QCm[t * 16 + 0];
      *(float4*)&qrow[4]  = *(const float4*)&QCm[t * 16 + 4];
      *(float4*)&qrow[8]  = *(const float4*)&QCm[t * 16 + 8];
      *(float4*)&qrow[12] = *(const float4*)&QCm[t * 16 + 12];
      *(float4*)&krow[0]  = *(const float4*)&KCm[t * 16 + 0];
      *(float4*)&krow[4]  = *(const float4*)&KCm[t * 16 + 4];
      *(float4*)&krow[8]  = *(const float4*)&KCm[t * 16 + 8];
      *(float4*)&krow[12] = *(const float4*)&KCm[t * 16 + 12];
      float2 qk = *(const float2*)&QKb[(t * 64 + lane) * 2];
      float V = slab[t * 256 + 64 + lane];
      float pred = qk.x, kh = qk.y;
      #pragma unroll
      for (int s = 0; s < t; s++) {
        pred = fmaf(qrow[s], g[s], pred);
        kh   = fmaf(krow[s], g[s], kh);
      }
      float d = V - pred;
      float e = wave_reduce_add_f32(d * d);
      float sur = __builtin_amdgcn_rcpf(1.f + __builtin_amdgcn_exp2f(e * -1.4426936f));
      g[t] = sur * (V - kh);
    }
    // ---- ph4a: H update: H = Pend * (H0 + sum_s w~_s g_s)
    #pragma unroll
    for (int s = 0; s < 16; s++) {
      float4 w0 = *(const float4*)&wt[s * 68 + (w << 4) + 0];
      float4 w1 = *(const float4*)&wt[s * 68 + (w << 4) + 4];
      float4 w2 = *(const float4*)&wt[s * 68 + (w << 4) + 8];
      float4 w3 = *(const float4*)&wt[s * 68 + (w << 4) + 12];
      H[0]  = fmaf(w0.x, g[s], H[0]);  H[1]  = fmaf(w0.y, g[s], H[1]);
      H[2]  = fmaf(w0.z, g[s], H[2]);  H[3]  = fmaf(w0.w, g[s], H[3]);
      H[4]  = fmaf(w1.x, g[s], H[4]);  H[5]  = fmaf(w1.y, g[s], H[5]);
      H[6]  = fmaf(w1.z, g[s], H[6]);  H[7]  = fmaf(w1.w, g[s], H[7]);
      H[8]  = fmaf(w2.x, g[s], H[8]);  H[9]  = fmaf(w2.y, g[s], H[9]);
      H[10] = fmaf(w2.z, g[s], H[10]); H[11] = fmaf(w2.w, g[s], H[11]);
      H[12] = fmaf(w3.x, g[s], H[12]); H[13] = fmaf(w3.y, g[s], H[13]);
      H[14] = fmaf(w3.z, g[s], H[14]); H[15] = fmaf(w3.w, g[s], H[15]);
    }
    {
      float4 p0 = *(const float4*)&Pt[15 * 64 + (w << 4) + 0];
      float4 p1 = *(const float4*)&Pt[15 * 64 + (w << 4) + 4];
      float4 p2 = *(const float4*)&Pt[15 * 64 + (w << 4) + 8];
      float4 p3 = *(const float4*)&Pt[15 * 64 + (w << 4) + 12];
      H[0]  *= p0.x; H[1]  *= p0.y; H[2]  *= p0.z; H[3]  *= p0.w;
      H[4]  *= p1.x; H[5]  *= p1.y; H[6]  *= p1.z; H[7]  *= p1.w;
      H[8]  *= p2.x; H[9]  *= p2.y; H[10] *= p2.z; H[11] *= p2.w;
      H[12] *= p3.x; H[13] *= p3.y; H[14] *= p3.z; H[15] *= p3.w;
      #pragma unroll
      for (int j = 0; j < 16; j++) H0t[((w << 4) + j) * 64 + lane] = H[j];
    }
    // ---- ph4b: y assembly for this wave's t-set; direct global store.
    #pragma unroll
    for (int i = 0; i < 4; i++) {
      const int t = w + (i << 2);
      float yrow[16];
      *(float4*)&yrow[0]  = *(const float4*)&YCm[t * 16 + 0];
      *(float4*)&yrow[4]  = *(const float4*)&YCm[t * 16 + 4];
      *(float4*)&yrow[8]  = *(const float4*)&YCm[t * 16 + 8];
      *(float4*)&yrow[12] = *(const float4*)&YCm[t * 16 + 12];
      float y = Yb[t * 64 + lane];
      #pragma unroll
      for (int s = 0; s < 16; s++) {
        float c = (s <= t) ? yrow[s] : 0.f;
        y = fmaf(c, g[s], y);
      }
      yb[(size_t)(t0 + t) * 64 + lane] = y;
    }
    __syncthreads();   // end of chunk: H0t stable, slab/tables free
  }
}

// ---------------------------------------------------------------------------
// Wo transpose (2048x64 -> 64x2048).
// ---------------------------------------------------------------------------
__global__ __launch_bounds__(256) void k_trans(const float* __restrict__ Wo,
                                               float* __restrict__ WoT) {
  int i = blockIdx.x * 256 + threadIdx.x;
  int d = i >> 11;
  int c = i & 2047;
  WoT[i] = Wo[(size_t)c * 64 + d];
}

// ---------------------------------------------------------------------------
// K3: RMS-norm over 64, * norm_w, then yn @ Wo^T. (y rows are complete now.)
// ---------------------------------------------------------------------------
__global__ __launch_bounds__(256) void k_out(const float* __restrict__ ypart,
    const float* __restrict__ norm_w, const float* __restrict__ WoT,
    float* __restrict__ out)
{
  __shared__ __align__(16) float yn[16 * 64];
  const int tid = threadIdx.x;
  const int r0  = blockIdx.x * 16;
  const int c0  = blockIdx.y * 512;
  {
    const int r = tid >> 4;
    const int d = (tid & 15) * 4;
    const float* yp = ypart + (size_t)(r0 + r) * 64;
    float4 yv = *(const float4*)(yp + d);
    float sq = yv.x * yv.x + yv.y * yv.y + yv.z * yv.z + yv.w * yv.w;
    sq += __shfl_xor(sq, 1, 64);
    sq += __shfl_xor(sq, 2, 64);
    sq += __shfl_xor(sq, 4, 64);
    sq += __shfl_xor(sq, 8, 64);
    float rms = rsqrtf(sq * (1.f / 64.f) + 1e-6f);
    float4 nw = *(const float4*)(norm_w + d);
    yn[r * 64 + d + 0] = yv.x * rms * nw.x;
    yn[r * 64 + d + 1] = yv.y * rms * nw.y;
    yn[r * 64 + d + 2] = yv.z * rms * nw.z;
    yn[r * 64 + d + 3] = yv.w * rms * nw.w;
  }
  __syncthreads();
  const int ctq = tid & 127;
  const int rt  = tid >> 7;
  float acc[8][4];
  #pragma unroll
  for (int r = 0; r < 8; r++) { acc[r][0] = 0.f; acc[r][1] = 0.f; acc[r][2] = 0.f; acc[r][3] = 0.f; }
  #pragma unroll 8
  for (int d = 0; d < 64; d++) {
    float4 wv = *(const float4*)(WoT + (size_t)d * 2048 + c0 + ctq * 4);
    #pragma unroll
    for (int r = 0; r < 8; r++) {
      float yv = yn[(rt * 8 + r) * 64 + d];
      acc[r][0] = fmaf(yv, wv.x, acc[r][0]);
      acc[r][1] = fmaf(yv, wv.y, acc[r][1]);
      acc[r][2] = fmaf(yv, wv.z, acc[r][2]);
      acc[r][3] = fmaf(yv, wv.w, acc[r][3]);
    }
  }
  #pragma unroll
  for (int r = 0; r < 8; r++) {
    float4 o; o.x = acc[r][0]; o.y = acc[r][1]; o.z = acc[r][2]; o.w = acc[r][3];
    *(float4*)(out + (size_t)(r0 + rt * 8 + r) * 2048 + c0 + ctq * 4) = o;
  }
}

extern "C" void kernel_launch(void* const* d_in, const int* in_sizes, int n_in,
                              void* d_out, int out_size, void* d_ws, size_t ws_size,
                              hipStream_t stream) {
  const float* x   = (const float*)d_in[0];
  const float* Wk  = (const float*)d_in[1];
  const float* Wv  = (const float*)d_in[2];
  const float* Wq  = (const float*)d_in[3];
  const float* Wa  = (const float*)d_in[4];
  const float* Wab = (const float*)d_in[5];
  const float* lam = (const float*)d_in[6];
  const float* nw  = (const float*)d_in[7];
  const float* Wo  = (const float*)d_in[8];
  float* out = (float*)d_out;

  float* wsf   = (float*)d_ws;
  float* proj  = wsf;                 // 4*2048*256 = 2,097,152 floats
  float* ypart = wsf + 2097152;       // 4*2048*64  =   524,288 floats
  float* WoT   = wsf + 2621440;       // 64*2048    =   131,072 floats

  k_trans<<<dim3(512), dim3(256), 0, stream>>>(Wo, WoT);
  k_proj <<<dim3(512), dim3(256), 0, stream>>>(x, Wk, Wv, Wq, Wa, Wab, lam, proj);
  k_scan <<<dim3(4),   dim3(256), 0, stream>>>(proj, ypart);
  k_out  <<<dim3(512, 4), dim3(256), 0, stream>>>(ypart, nw, WoT, out);
}